// Round 8
// baseline (152.191 us; speedup 1.0000x reference)
//
#include <hip/hip_runtime.h>

#define NN 4096
#define DIM 128
#define TN 64            // q-rows per block (4 waves x 16 rows)
#define TM 32            // m-tile size
#define NSPLIT 12        // split-m factor (atomic combine); grid = 64*12 = 768 = 3/CU exactly

typedef __attribute__((ext_vector_type(8))) short bf16x8;
typedef __attribute__((ext_vector_type(4))) float f32x4;

#define HRS 136                        // Hrow stride (ushorts, 272 B, 16B-mult)
#define HCS 40                         // Hcol stride (ushorts, 80 B, 16B-mult)
#define HROW_USH (TM * HRS)            // 32*136 = 4352
#define HCOL_USH (128 * HCS)           // 128*40 = 5120
#define TILE_USH 9728                  // 4352+5120 = 9472, padded to 19*512 ush = 19456 B
#define TILE_CHUNKS 19                 // 19456 / 1024
#define PST 40                         // P scratch row stride (ushorts, 16B-mult)

__device__ inline unsigned short f2bf(float x) {
    union { float f; unsigned u; } v; v.f = x;
    unsigned r = v.u + 0x7FFFu + ((v.u >> 16) & 1u);
    return (unsigned short)(r >> 16);
}

// async global->LDS DMA, 16 B/lane, dest = wave-uniform base + lane*16
__device__ inline void dma16(const void* g, void* l) {
    __builtin_amdgcn_global_load_lds(
        (const __attribute__((address_space(1))) void*)g,
        (__attribute__((address_space(3))) void*)l,
        16, 0, 0);
}

// ---- prep (1024 blocks = 128 tiles x 8 slices):
//      hidden fp32 -> Hpack[128 tiles][Hrow 32x136 | Hcol 128x40 | pad] bf16 ----
__global__ __launch_bounds__(256) void prep_pack_kernel(
    const float* __restrict__ hidden,
    unsigned short* __restrict__ Hpack)
{
    __shared__ unsigned short T[16][HCS];   // transpose slice [d][m]
    const int tid = threadIdx.x;
    const int t0  = blockIdx.x >> 3;   // tile 0..127
    const int s   = blockIdx.x & 7;    // slice 0..7
    const int m0  = t0 * TM;
    unsigned short* rowdst = Hpack + (size_t)t0 * TILE_USH;
    unsigned short* coldst = rowdst + HROW_USH;

    if (tid < 128) {
        // rows part: rows [4s, 4s+4) x 128 d -> rowdst (waves 0,1)
        int row = tid >> 5;            // 0..3
        int c4  = (tid & 31) * 4;      // 0..124
        float4 v = *(const float4*)(hidden + (size_t)(m0 + 4 * s + row) * DIM + c4);
        ushort4 o;
        o.x = f2bf(v.x); o.y = f2bf(v.y); o.z = f2bf(v.z); o.w = f2bf(v.w);
        *(ushort4*)(rowdst + (4 * s + row) * HRS + c4) = o;
    } else {
        // cols part: d in [16s, 16s+16) x 32 m -> T transposed (waves 2,3)
        int t2 = tid - 128;
        int m  = t2 >> 2;              // 0..31
        int dc = (t2 & 3) * 4;         // 0..12
        float4 v = *(const float4*)(hidden + (size_t)(m0 + m) * DIM + 16 * s + dc);
        T[dc + 0][m] = f2bf(v.x);
        T[dc + 1][m] = f2bf(v.y);
        T[dc + 2][m] = f2bf(v.z);
        T[dc + 3][m] = f2bf(v.w);
    }
    __syncthreads();
    if (tid < 64) {
        int d  = tid >> 2;             // 0..15
        int c8 = (tid & 3) * 8;        // m chunk of 8
        uint4 v = *(const uint4*)(&T[d][c8]);
        *(uint4*)(coldst + (16 * s + d) * HCS + c8) = v;
    }
}

// ---- main (round 8): R6's proven template (wave-private rows, no mid-tile
//      barrier, double-buffered DMA, one __syncthreads/tile) with TM 64->32:
//      LDS 44032 B -> 3 blocks/CU = 12 waves/CU = 3 waves/SIMD, the first
//      CLEAN test of the TLP hypothesis (R1/R3/R4's 16-wave runs were
//      spill-poisoned at 64 VGPR; R7's 12-wave single-buffer raced).
//      Grid 768 = 3/CU x 256 CU exactly -> single residency round, no
//      1-block/CU drain tail (why NSPLIT=12 with 11/10-tile blocks, not 16).
//      Keep __launch_bounds__(256,2) verbatim: only decl with proven clean
//      regalloc (104 VGPR); per-wave state shrinks further here (avc 8 not 16)
//      so the 128-VGPR / 16-wave HW cap stays cleared. ----
__global__ __launch_bounds__(256, 2) void gat_flash_kernel(
    const float* __restrict__ hidden,        // fp32 (for Q fragments)
    const unsigned short* __restrict__ Hpack,
    const int*   __restrict__ adj,           // [NN][NN] int32
    const float* __restrict__ W,
    const float* __restrict__ bvec,
    float*       __restrict__ Onum,          // [NN][DIM] fp32, pre-zeroed
    float*       __restrict__ lsum)          // [NN] fp32, pre-zeroed
{
    __shared__ __align__(16) unsigned short HH[2][TILE_USH];   // 38912 B
    __shared__ __align__(16) unsigned short Plc[4][16 * PST];  // 5120 B

    const int tid  = threadIdx.x;
    const int w    = tid >> 6;         // 0..3: wave = 16-row group
    const int lane = tid & 63;
    const int g    = lane >> 4;
    const int l15  = lane & 15;
    const int blk  = blockIdx.x;
    const int nbr  = blk / NSPLIT;     // 0..63 row-group of 64
    const int q12  = blk - nbr * NSPLIT;   // 0..11 column split
    const int n0   = nbr * TN;
    // uneven split of 128 tiles over 12 blocks: first 8 get 11, rest 10
    const int tstart = (q12 < 8) ? 11 * q12 : 88 + 10 * (q12 - 8);
    const int cnt    = (q12 < 8) ? 11 : 10;
    const int lofs = lane * 16;

    const float b0 = bvec[0], b1 = bvec[1], b2 = bvec[2], b3 = bvec[3];

    // ---- prologue: DMA tile tstart -> HH[0]; overlaps Af build + adj loads ----
    {
        const char* src = (const char*)(Hpack + (size_t)tstart * TILE_USH);
        char* dst = (char*)&HH[0][0];
        #pragma unroll
        for (int it = 0; it < 5; ++it) {
            int chunk = it * 4 + w;
            if (chunk < TILE_CHUNKS)
                dma16(src + chunk * 1024 + lofs, dst + chunk * 1024);
        }
    }

    // ---- Af built directly from global (h (.) W_k), no LDS staging ----
    bf16x8 Af[4][4];
    {
        const int qrow = n0 + w * 16 + l15;
        #pragma unroll
        for (int ks = 0; ks < 4; ++ks) {
            const float* hp = hidden + (size_t)qrow * DIM + ks * 32 + 8 * g;
            float4 h0 = *(const float4*)(hp);
            float4 h1 = *(const float4*)(hp + 4);
            #pragma unroll
            for (int k = 0; k < 4; ++k) {
                const float* wp = W + k * DIM + ks * 32 + 8 * g;
                float4 w0 = *(const float4*)(wp);
                float4 w1 = *(const float4*)(wp + 4);
                bf16x8 a;
                a[0] = (short)f2bf(h0.x * w0.x); a[1] = (short)f2bf(h0.y * w0.y);
                a[2] = (short)f2bf(h0.z * w0.z); a[3] = (short)f2bf(h0.w * w0.w);
                a[4] = (short)f2bf(h1.x * w1.x); a[5] = (short)f2bf(h1.y * w1.y);
                a[6] = (short)f2bf(h1.z * w1.z); a[7] = (short)f2bf(h1.w * w1.w);
                Af[k][ks] = a;
            }
        }
    }

    float lrow[4] = {0.f, 0.f, 0.f, 0.f};
    f32x4 Oacc[8];
    #pragma unroll
    for (int dt = 0; dt < 8; ++dt) Oacc[dt] = (f32x4){0.f, 0.f, 0.f, 0.f};

    // adj codes for tile 0: 8 coalesced int loads/lane (rows 4g+t, cols ch*16+l15)
    const size_t arow = (size_t)(n0 + w * 16 + 4 * g) * NN;
    int avc[8], avn[8];
    #pragma unroll
    for (int ch = 0; ch < 2; ++ch)
        #pragma unroll
        for (int t = 0; t < 4; ++t)
            avc[ch * 4 + t] = adj[arow + (size_t)t * NN + (size_t)tstart * TM + ch * 16 + l15];

    __syncthreads();   // drains tile-0 DMA (vmcnt); only barrier before loop

    unsigned short* Pw = &Plc[w][0];   // wave-private P scratch [16][PST]

    for (int tile = 0; tile < cnt; ++tile) {
        const int cur = tile & 1;
        const int nxt = cur ^ 1;

        // ---- issue next-tile DMA into the OTHER buffer; in flight all tile ----
        if (tile + 1 < cnt) {
            const char* src = (const char*)(Hpack + (size_t)(tstart + tile + 1) * TILE_USH);
            char* dst = (char*)&HH[nxt][0];
            #pragma unroll
            for (int it = 0; it < 5; ++it) {
                int chunk = it * 4 + w;
                if (chunk < TILE_CHUNKS)
                    dma16(src + chunk * 1024 + lofs, dst + chunk * 1024);
            }
        }

        // ---- QK + select + exp, one 16-col ch slice at a time ----
        #pragma unroll
        for (int ch = 0; ch < 2; ++ch) {
            f32x4 S[4];
            #pragma unroll
            for (int k = 0; k < 4; ++k) S[k] = (f32x4){0.f, 0.f, 0.f, 0.f};
            #pragma unroll
            for (int ks = 0; ks < 4; ++ks) {
                bf16x8 B = *(const bf16x8*)&HH[cur][(ch * 16 + l15) * HRS + ks * 32 + 8 * g];
                #pragma unroll
                for (int k = 0; k < 4; ++k)
                    S[k] = __builtin_amdgcn_mfma_f32_16x16x32_bf16(Af[k][ks], B, S[k], 0, 0, 0);
            }
            #pragma unroll
            for (int t = 0; t < 4; ++t) {
                int a = avc[ch * 4 + t];
                float s = S[0][t] + b0;
                s = (a == 2) ? S[1][t] + b1 : s;
                s = (a == 3) ? S[2][t] + b2 : s;
                s = (a == 4) ? S[3][t] + b3 : s;
                float e = fmaxf(s, 0.2f * s);
                float p = __expf(e);           // no-max softmax; scores bounded
                p = (a == 0) ? 0.f : p;
                lrow[t] += p;
                Pw[(4 * g + t) * PST + ch * 16 + l15] = f2bf(p);
            }
        }

        // ---- adj prefetch for next tile (hidden by PV + next QK) ----
        if (tile + 1 < cnt) {
            #pragma unroll
            for (int ch = 0; ch < 2; ++ch)
                #pragma unroll
                for (int t = 0; t < 4; ++t)
                    avn[ch * 4 + t] = adj[arow + (size_t)t * NN + (size_t)(tstart + tile + 1) * TM + ch * 16 + l15];
        }

        // ---- PV: no barrier — Pw is wave-private (same-wave DS order);
        //      K = TM = 32 -> single MFMA per d-tile ----
        {
            bf16x8 Pa = *(const bf16x8*)&Pw[l15 * PST + 8 * g];
            #pragma unroll
            for (int dt = 0; dt < 8; ++dt) {
                bf16x8 Bv = *(const bf16x8*)&HH[cur][HROW_USH + (dt * 16 + l15) * HCS + 8 * g];
                Oacc[dt] = __builtin_amdgcn_mfma_f32_16x16x32_bf16(Pa, Bv, Oacc[dt], 0, 0, 0);
            }
        }

        #pragma unroll
        for (int i = 0; i < 8; ++i) avc[i] = avn[i];
        __syncthreads();   // vmcnt(0) drain == "HH[nxt] staged"; buffer swap
    }

    // ---- epilogue: rows wave-private; O via fp32 atomics (12 adds/cell) ----
    #pragma unroll
    for (int t = 0; t < 4; ++t) {
        float v = lrow[t];
        v += __shfl_xor(v, 1); v += __shfl_xor(v, 2);
        v += __shfl_xor(v, 4); v += __shfl_xor(v, 8);
        if (l15 == 0) atomicAdd(&lsum[n0 + w * 16 + 4 * g + t], v);
    }
    const int orow0 = n0 + w * 16 + 4 * g;
    #pragma unroll
    for (int dt = 0; dt < 8; ++dt)
        #pragma unroll
        for (int t = 0; t < 4; ++t)
            atomicAdd(&Onum[(size_t)(orow0 + t) * DIM + dt * 16 + l15], Oacc[dt][t]);
}

// ---- combine: trivial divide ----
__global__ __launch_bounds__(256) void combine_kernel(
    const float* __restrict__ Onum, const float* __restrict__ lsum,
    float* __restrict__ out)
{
    int idx = blockIdx.x * 256 + threadIdx.x;
    out[idx] = Onum[idx] / lsum[idx >> 7];
}

extern "C" void kernel_launch(void* const* d_in, const int* in_sizes, int n_in,
                              void* d_out, int out_size, void* d_ws, size_t ws_size,
                              hipStream_t stream) {
    const float* hidden = (const float*)d_in[0];
    const int*   adj    = (const int*)d_in[1];
    const float* W      = (const float*)d_in[2];
    const float* b      = (const float*)d_in[3];
    float* out = (float*)d_out;

    char* ws = (char*)d_ws;
    unsigned short* Hpack = (unsigned short*)ws;                 // 128*9728*2 = 2.38 MB
    float* Onum = (float*)(ws + (4u << 20));                     // 2 MB
    float* lsum = (float*)(ws + (6u << 20));                     // 16 KB
    // zero Onum + lsum in one contiguous memset (graph-capturable)
    hipMemsetAsync(ws + (4u << 20), 0, (2u << 20) + NN * sizeof(float), stream);

    prep_pack_kernel<<<(NN / TM) * 8, 256, 0, stream>>>(hidden, Hpack);
    gat_flash_kernel<<<64 * NSPLIT, 256, 0, stream>>>(hidden, Hpack, adj, W, b, Onum, lsum);
    combine_kernel<<<NN * DIM / 256, 256, 0, stream>>>(Onum, lsum, out);
}

// Round 9
// 137.467 us; speedup vs baseline: 1.1071x; 1.1071x over previous
//
#include <hip/hip_runtime.h>

#define NN 4096
#define DIM 128
#define TN 64            // q-rows per block (4 waves x 16 rows)
#define TM 64            // m-tile size
#define NSPLIT 8         // split-m factor (atomic combine)
#define NTILES 8         // tiles per block (64 global tiles / 8)

typedef __attribute__((ext_vector_type(8))) short bf16x8;
typedef __attribute__((ext_vector_type(4))) float f32x4;

#define HRS 136                        // Hrow stride (ushorts, 272 B, 16B-mult)
#define HCS 72                         // Hcol stride (ushorts, 144 B, 16B-mult)
#define HROW_USH (TM * HRS)            // 64*136 = 8704
#define HCOL_USH (128 * HCS)           // 128*72 = 9216
#define TILE_USH (HROW_USH + HCOL_USH) // 17920 ushorts = 35840 B
#define TILE_CHUNKS 35                 // 35840 / 1024
#define PST 72                         // P scratch row stride (ushorts, 16B-mult)

__device__ inline unsigned short f2bf(float x) {
    union { float f; unsigned u; } v; v.f = x;
    unsigned r = v.u + 0x7FFFu + ((v.u >> 16) & 1u);
    return (unsigned short)(r >> 16);
}

// async global->LDS DMA, 16 B/lane, dest = wave-uniform base + lane*16
__device__ inline void dma16(const void* g, void* l) {
    __builtin_amdgcn_global_load_lds(
        (const __attribute__((address_space(1))) void*)g,
        (__attribute__((address_space(3))) void*)l,
        16, 0, 0);
}

// ---- prep (512 blocks = 64 tiles x 8 slices):
//      hidden fp32 -> Hpack[64 tiles][Hrow 64x136 | Hcol 128x72] bf16 ----
__global__ __launch_bounds__(256) void prep_pack_kernel(
    const float* __restrict__ hidden,
    unsigned short* __restrict__ Hpack)
{
    __shared__ unsigned short T[16][HCS];   // transpose slice [d][m]
    const int tid = threadIdx.x;
    const int t0  = blockIdx.x >> 3;   // tile 0..63
    const int s   = blockIdx.x & 7;    // slice 0..7
    const int m0  = t0 * TM;
    unsigned short* rowdst = Hpack + (size_t)t0 * TILE_USH;
    unsigned short* coldst = rowdst + HROW_USH;

    // rows part: rows [8s, 8s+8) x 128 d -> rowdst
    {
        int row = tid >> 5;            // 0..7
        int c4  = (tid & 31) * 4;      // 0..124
        float4 v = *(const float4*)(hidden + (size_t)(m0 + 8 * s + row) * DIM + c4);
        ushort4 o;
        o.x = f2bf(v.x); o.y = f2bf(v.y); o.z = f2bf(v.z); o.w = f2bf(v.w);
        *(ushort4*)(rowdst + (8 * s + row) * HRS + c4) = o;
    }
    // cols part: d in [16s, 16s+16) x 64 m -> T (transposed)
    {
        int m  = tid >> 2;             // 0..63
        int dc = (tid & 3) * 4;        // 0..12
        float4 v = *(const float4*)(hidden + (size_t)(m0 + m) * DIM + 16 * s + dc);
        T[dc + 0][m] = f2bf(v.x);
        T[dc + 1][m] = f2bf(v.y);
        T[dc + 2][m] = f2bf(v.z);
        T[dc + 3][m] = f2bf(v.w);
    }
    __syncthreads();
    if (tid < 128) {
        int d  = tid >> 3;             // 0..15
        int c8 = (tid & 7) * 8;        // m chunk of 8
        uint4 v = *(const uint4*)(&T[d][c8]);
        *(uint4*)(coldst + (16 * s + d) * HCS + c8) = v;
    }
}

// ---- main (round 9): R6 champion (45.2 us) + two stall-removers.
//      (1) tile loop unrolled x2 with STATIC ping-pong: HH[0]/HH[1] and
//          avcA/avcB are compile-time — kills the 16-reg avc=avn copy whose
//          implicit vmcnt dependency drained the adj prefetch inside every
//          tile, and removes runtime cur/nxt addressing (rule #20).
//      (2) T5 s_setprio(1) around the QK and PV MFMA clusters — R6's
//          barrier-free waves genuinely desync within a tile (attn-like
//          role diversity, the regime where setprio measured +4-7%).
//      Everything else byte-identical to R6: wave-private rows, no mid-tile
//      barrier, double-buffered DMA, one __syncthreads/tile, atomic combine.
__global__ __launch_bounds__(256, 2) void gat_flash_kernel(
    const float* __restrict__ hidden,        // fp32 (for Q fragments)
    const unsigned short* __restrict__ Hpack,
    const int*   __restrict__ adj,           // [NN][NN] int32
    const float* __restrict__ W,
    const float* __restrict__ bvec,
    float*       __restrict__ Onum,          // [NN][DIM] fp32, pre-zeroed
    float*       __restrict__ lsum)          // [NN] fp32, pre-zeroed
{
    __shared__ __align__(16) unsigned short HH[2][TILE_USH];   // 71680 B
    __shared__ __align__(16) unsigned short Plc[4][16 * PST];  // 9216 B

    const int tid  = threadIdx.x;
    const int w    = tid >> 6;         // 0..3: wave = 16-row group
    const int lane = tid & 63;
    const int g    = lane >> 4;
    const int l15  = lane & 15;
    const int blk  = blockIdx.x;
    const int nbr  = blk >> 3;         // 0..63 row-group of 64
    const int q8   = blk & 7;          // 0..7 column eighth (== XCD id: L2-local)
    const int n0   = nbr * TN;
    const int gt0  = q8 * NTILES;      // first global tile (of 64)
    const int lofs = lane * 16;

    const float b0 = bvec[0], b1 = bvec[1], b2 = bvec[2], b3 = bvec[3];

    // ---- prologue: DMA tile 0 -> HH[0]; overlaps Af build + adj loads ----
    {
        const char* src = (const char*)(Hpack + (size_t)gt0 * TILE_USH);
        char* dst = (char*)&HH[0][0];
        #pragma unroll
        for (int it = 0; it < 9; ++it) {
            int chunk = it * 4 + w;
            if (chunk < TILE_CHUNKS)
                dma16(src + chunk * 1024 + lofs, dst + chunk * 1024);
        }
    }

    // ---- Af built directly from global (h (.) W_k), no LDS staging ----
    bf16x8 Af[4][4];
    {
        const int qrow = n0 + w * 16 + l15;
        #pragma unroll
        for (int ks = 0; ks < 4; ++ks) {
            const float* hp = hidden + (size_t)qrow * DIM + ks * 32 + 8 * g;
            float4 h0 = *(const float4*)(hp);
            float4 h1 = *(const float4*)(hp + 4);
            #pragma unroll
            for (int k = 0; k < 4; ++k) {
                const float* wp = W + k * DIM + ks * 32 + 8 * g;
                float4 w0 = *(const float4*)(wp);
                float4 w1 = *(const float4*)(wp + 4);
                bf16x8 a;
                a[0] = (short)f2bf(h0.x * w0.x); a[1] = (short)f2bf(h0.y * w0.y);
                a[2] = (short)f2bf(h0.z * w0.z); a[3] = (short)f2bf(h0.w * w0.w);
                a[4] = (short)f2bf(h1.x * w1.x); a[5] = (short)f2bf(h1.y * w1.y);
                a[6] = (short)f2bf(h1.z * w1.z); a[7] = (short)f2bf(h1.w * w1.w);
                Af[k][ks] = a;
            }
        }
    }

    float lrow[4] = {0.f, 0.f, 0.f, 0.f};
    f32x4 Oacc[8];
    #pragma unroll
    for (int dt = 0; dt < 8; ++dt) Oacc[dt] = (f32x4){0.f, 0.f, 0.f, 0.f};

    // adj codes for tile 0 -> avcA: 16 coalesced int loads/lane
    const size_t arow = (size_t)(n0 + w * 16 + 4 * g) * NN;
    int avcA[16], avcB[16];
    #pragma unroll
    for (int ch = 0; ch < 4; ++ch)
        #pragma unroll
        for (int t = 0; t < 4; ++t)
            avcA[ch * 4 + t] = adj[arow + (size_t)t * NN + gt0 * TM + ch * 16 + l15];

    __syncthreads();   // drains tile-0 DMA (vmcnt); only barrier before loop

    unsigned short* Pw = &Plc[w][0];   // wave-private P scratch [16][PST]

    // One tile body. CUR/NXT are literal 0/1; AVC consumed, AVN prefetched.
    // Order kept from R6: DMA issue -> QK+select -> adj prefetch -> PV -> barrier.
#define TILE_BODY(CUR, NXT, AVC, AVN, TCUR, PREF_OK)                               \
    {                                                                              \
        if (PREF_OK) {                                                             \
            const char* src = (const char*)(Hpack + (size_t)(gt0 + (TCUR) + 1) * TILE_USH); \
            char* dst = (char*)&HH[NXT][0];                                        \
            _Pragma("unroll")                                                      \
            for (int it = 0; it < 9; ++it) {                                       \
                int chunk = it * 4 + w;                                            \
                if (chunk < TILE_CHUNKS)                                           \
                    dma16(src + chunk * 1024 + lofs, dst + chunk * 1024);          \
            }                                                                      \
        }                                                                          \
        _Pragma("unroll")                                                          \
        for (int ch = 0; ch < 4; ++ch) {                                           \
            f32x4 S[4];                                                            \
            _Pragma("unroll")                                                      \
            for (int k = 0; k < 4; ++k) S[k] = (f32x4){0.f, 0.f, 0.f, 0.f};        \
            __builtin_amdgcn_s_setprio(1);                                         \
            _Pragma("unroll")                                                      \
            for (int ks = 0; ks < 4; ++ks) {                                       \
                bf16x8 B = *(const bf16x8*)&HH[CUR][(ch * 16 + l15) * HRS + ks * 32 + 8 * g]; \
                _Pragma("unroll")                                                  \
                for (int k = 0; k < 4; ++k)                                        \
                    S[k] = __builtin_amdgcn_mfma_f32_16x16x32_bf16(Af[k][ks], B, S[k], 0, 0, 0); \
            }                                                                      \
            __builtin_amdgcn_s_setprio(0);                                         \
            _Pragma("unroll")                                                      \
            for (int t = 0; t < 4; ++t) {                                          \
                int a = (AVC)[ch * 4 + t];                                         \
                float s = S[0][t] + b0;                                            \
                s = (a == 2) ? S[1][t] + b1 : s;                                   \
                s = (a == 3) ? S[2][t] + b2 : s;                                   \
                s = (a == 4) ? S[3][t] + b3 : s;                                   \
                float e = fmaxf(s, 0.2f * s);                                      \
                float p = __expf(e);                                               \
                p = (a == 0) ? 0.f : p;                                            \
                lrow[t] += p;                                                      \
                Pw[(4 * g + t) * PST + ch * 16 + l15] = f2bf(p);                   \
            }                                                                      \
        }                                                                          \
        if (PREF_OK) {                                                             \
            _Pragma("unroll")                                                      \
            for (int ch = 0; ch < 4; ++ch)                                         \
                _Pragma("unroll")                                                  \
                for (int t = 0; t < 4; ++t)                                        \
                    (AVN)[ch * 4 + t] = adj[arow + (size_t)t * NN + (size_t)(gt0 + (TCUR) + 1) * TM + ch * 16 + l15]; \
        }                                                                          \
        __builtin_amdgcn_s_setprio(1);                                             \
        _Pragma("unroll")                                                          \
        for (int kc = 0; kc < 2; ++kc) {                                           \
            bf16x8 Pa = *(const bf16x8*)&Pw[l15 * PST + kc * 32 + 8 * g];          \
            _Pragma("unroll")                                                      \
            for (int dt = 0; dt < 8; ++dt) {                                       \
                bf16x8 Bv = *(const bf16x8*)&HH[CUR][HROW_USH + (dt * 16 + l15) * HCS + kc * 32 + 8 * g]; \
                Oacc[dt] = __builtin_amdgcn_mfma_f32_16x16x32_bf16(Pa, Bv, Oacc[dt], 0, 0, 0); \
            }                                                                      \
        }                                                                          \
        __builtin_amdgcn_s_setprio(0);                                             \
        __syncthreads();   /* vmcnt(0) drain == "HH[NXT] staged"; buffer swap */   \
    }

    #pragma unroll
    for (int tt = 0; tt < NTILES; tt += 2) {
        TILE_BODY(0, 1, avcA, avcB, tt, 1)
        TILE_BODY(1, 0, avcB, avcA, tt + 1, (tt + 2 < NTILES))
    }
#undef TILE_BODY

    // ---- epilogue: rows wave-private; O via fp32 atomics (8 adds/cell) ----
    #pragma unroll
    for (int t = 0; t < 4; ++t) {
        float v = lrow[t];
        v += __shfl_xor(v, 1); v += __shfl_xor(v, 2);
        v += __shfl_xor(v, 4); v += __shfl_xor(v, 8);
        if (l15 == 0) atomicAdd(&lsum[n0 + w * 16 + 4 * g + t], v);
    }
    const int orow0 = n0 + w * 16 + 4 * g;
    #pragma unroll
    for (int dt = 0; dt < 8; ++dt)
        #pragma unroll
        for (int t = 0; t < 4; ++t)
            atomicAdd(&Onum[(size_t)(orow0 + t) * DIM + dt * 16 + l15], Oacc[dt][t]);
}

// ---- combine: trivial divide ----
__global__ __launch_bounds__(256) void combine_kernel(
    const float* __restrict__ Onum, const float* __restrict__ lsum,
    float* __restrict__ out)
{
    int idx = blockIdx.x * 256 + threadIdx.x;
    out[idx] = Onum[idx] / lsum[idx >> 7];
}

extern "C" void kernel_launch(void* const* d_in, const int* in_sizes, int n_in,
                              void* d_out, int out_size, void* d_ws, size_t ws_size,
                              hipStream_t stream) {
    const float* hidden = (const float*)d_in[0];
    const int*   adj    = (const int*)d_in[1];
    const float* W      = (const float*)d_in[2];
    const float* b      = (const float*)d_in[3];
    float* out = (float*)d_out;

    char* ws = (char*)d_ws;
    unsigned short* Hpack = (unsigned short*)ws;                 // 2.29 MB
    float* Onum = (float*)(ws + (4u << 20));                     // 2 MB
    float* lsum = (float*)(ws + (6u << 20));                     // 16 KB
    // zero Onum + lsum in one contiguous memset (graph-capturable)
    hipMemsetAsync(ws + (4u << 20), 0, (2u << 20) + NN * sizeof(float), stream);

    prep_pack_kernel<<<(NN / TM) * 8, 256, 0, stream>>>(hidden, Hpack);
    gat_flash_kernel<<<(NN / TN) * NSPLIT, 256, 0, stream>>>(hidden, Hpack, adj, W, b, Onum, lsum);
    combine_kernel<<<NN * DIM / 256, 256, 0, stream>>>(Onum, lsum, out);
}

// Round 10
// 132.786 us; speedup vs baseline: 1.1461x; 1.0352x over previous
//
#include <hip/hip_runtime.h>

#define NN 4096
#define DIM 128
#define TN 64            // q-rows per block (4 waves x 16 rows)
#define TM 64            // m-tile size
#define NSPLIT 8         // split-m factor (atomic combine)
#define NTILES 8         // tiles per block (64 global tiles / 8)

typedef __attribute__((ext_vector_type(8))) short bf16x8;
typedef __attribute__((ext_vector_type(4))) float f32x4;

#define HRS 136                        // Hrow stride (ushorts, 272 B, 16B-mult)
#define HCS 72                         // Hcol stride (ushorts, 144 B, 16B-mult)
#define HROW_USH (TM * HRS)            // 64*136 = 8704
#define HCOL_USH (128 * HCS)           // 128*72 = 9216
#define TILE_USH (HROW_USH + HCOL_USH) // 17920 ushorts = 35840 B
#define TILE_CHUNKS 35                 // 35840 / 1024
#define PST 72                         // P scratch row stride (ushorts, 16B-mult)

__device__ inline unsigned short f2bf(float x) {
    union { float f; unsigned u; } v; v.f = x;
    unsigned r = v.u + 0x7FFFu + ((v.u >> 16) & 1u);
    return (unsigned short)(r >> 16);
}

// async global->LDS DMA, 16 B/lane, dest = wave-uniform base + lane*16
__device__ inline void dma16(const void* g, void* l) {
    __builtin_amdgcn_global_load_lds(
        (const __attribute__((address_space(1))) void*)g,
        (__attribute__((address_space(3))) void*)l,
        16, 0, 0);
}

// ---- prep (512 blocks = 64 tiles x 8 slices):
//      hidden fp32 -> Hpack[64 tiles][Hrow 64x136 | Hcol 128x72] bf16 ----
__global__ __launch_bounds__(256) void prep_pack_kernel(
    const float* __restrict__ hidden,
    unsigned short* __restrict__ Hpack)
{
    __shared__ unsigned short T[16][HCS];   // transpose slice [d][m]
    const int tid = threadIdx.x;
    const int t0  = blockIdx.x >> 3;   // tile 0..63
    const int s   = blockIdx.x & 7;    // slice 0..7
    const int m0  = t0 * TM;
    unsigned short* rowdst = Hpack + (size_t)t0 * TILE_USH;
    unsigned short* coldst = rowdst + HROW_USH;

    // rows part: rows [8s, 8s+8) x 128 d -> rowdst
    {
        int row = tid >> 5;            // 0..7
        int c4  = (tid & 31) * 4;      // 0..124
        float4 v = *(const float4*)(hidden + (size_t)(m0 + 8 * s + row) * DIM + c4);
        ushort4 o;
        o.x = f2bf(v.x); o.y = f2bf(v.y); o.z = f2bf(v.z); o.w = f2bf(v.w);
        *(ushort4*)(rowdst + (8 * s + row) * HRS + c4) = o;
    }
    // cols part: d in [16s, 16s+16) x 64 m -> T (transposed)
    {
        int m  = tid >> 2;             // 0..63
        int dc = (tid & 3) * 4;        // 0..12
        float4 v = *(const float4*)(hidden + (size_t)(m0 + m) * DIM + 16 * s + dc);
        T[dc + 0][m] = f2bf(v.x);
        T[dc + 1][m] = f2bf(v.y);
        T[dc + 2][m] = f2bf(v.z);
        T[dc + 3][m] = f2bf(v.w);
    }
    __syncthreads();
    if (tid < 128) {
        int d  = tid >> 3;             // 0..15
        int c8 = (tid & 7) * 8;        // m chunk of 8
        uint4 v = *(const uint4*)(&T[d][c8]);
        *(uint4*)(coldst + (16 * s + d) * HCS + c8) = v;
    }
}

// ---- main (round 10): R6 champion VERBATIM + s_setprio(1/0) around the QK
//      and PV MFMA clusters — nothing else. R9's x2 unroll pushed regalloc
//      to the 128 cap and spilled (+6 MB WRITE_SIZE); reverted. setprio adds
//      zero register pressure, so this is the clean single-variable T5 test
//      in its applicable regime (barrier-free waves with role diversity).
//      Structure: wave-private rows, no mid-tile barrier, double-buffered
//      DMA, one __syncthreads/tile, atomic split-m combine. ----
__global__ __launch_bounds__(256, 2) void gat_flash_kernel(
    const float* __restrict__ hidden,        // fp32 (for Q fragments)
    const unsigned short* __restrict__ Hpack,
    const int*   __restrict__ adj,           // [NN][NN] int32
    const float* __restrict__ W,
    const float* __restrict__ bvec,
    float*       __restrict__ Onum,          // [NN][DIM] fp32, pre-zeroed
    float*       __restrict__ lsum)          // [NN] fp32, pre-zeroed
{
    __shared__ __align__(16) unsigned short HH[2][TILE_USH];   // 71680 B
    __shared__ __align__(16) unsigned short Plc[4][16 * PST];  // 9216 B

    const int tid  = threadIdx.x;
    const int w    = tid >> 6;         // 0..3: wave = 16-row group
    const int lane = tid & 63;
    const int g    = lane >> 4;
    const int l15  = lane & 15;
    const int blk  = blockIdx.x;
    const int nbr  = blk >> 3;         // 0..63 row-group of 64
    const int q8   = blk & 7;          // 0..7 column eighth (== XCD id: L2-local)
    const int n0   = nbr * TN;
    const int gt0  = q8 * NTILES;      // first global tile (of 64)
    const int lofs = lane * 16;

    const float b0 = bvec[0], b1 = bvec[1], b2 = bvec[2], b3 = bvec[3];

    // ---- prologue: DMA tile 0 -> HH[0]; overlaps Af build + adj loads ----
    {
        const char* src = (const char*)(Hpack + (size_t)gt0 * TILE_USH);
        char* dst = (char*)&HH[0][0];
        #pragma unroll
        for (int it = 0; it < 9; ++it) {
            int chunk = it * 4 + w;
            if (chunk < TILE_CHUNKS)
                dma16(src + chunk * 1024 + lofs, dst + chunk * 1024);
        }
    }

    // ---- Af built directly from global (h (.) W_k), no LDS staging ----
    bf16x8 Af[4][4];
    {
        const int qrow = n0 + w * 16 + l15;
        #pragma unroll
        for (int ks = 0; ks < 4; ++ks) {
            const float* hp = hidden + (size_t)qrow * DIM + ks * 32 + 8 * g;
            float4 h0 = *(const float4*)(hp);
            float4 h1 = *(const float4*)(hp + 4);
            #pragma unroll
            for (int k = 0; k < 4; ++k) {
                const float* wp = W + k * DIM + ks * 32 + 8 * g;
                float4 w0 = *(const float4*)(wp);
                float4 w1 = *(const float4*)(wp + 4);
                bf16x8 a;
                a[0] = (short)f2bf(h0.x * w0.x); a[1] = (short)f2bf(h0.y * w0.y);
                a[2] = (short)f2bf(h0.z * w0.z); a[3] = (short)f2bf(h0.w * w0.w);
                a[4] = (short)f2bf(h1.x * w1.x); a[5] = (short)f2bf(h1.y * w1.y);
                a[6] = (short)f2bf(h1.z * w1.z); a[7] = (short)f2bf(h1.w * w1.w);
                Af[k][ks] = a;
            }
        }
    }

    float lrow[4] = {0.f, 0.f, 0.f, 0.f};
    f32x4 Oacc[8];
    #pragma unroll
    for (int dt = 0; dt < 8; ++dt) Oacc[dt] = (f32x4){0.f, 0.f, 0.f, 0.f};

    // adj codes for tile 0: 16 coalesced int loads/lane
    const size_t arow = (size_t)(n0 + w * 16 + 4 * g) * NN;
    int avc[16], avn[16];
    #pragma unroll
    for (int ch = 0; ch < 4; ++ch)
        #pragma unroll
        for (int t = 0; t < 4; ++t)
            avc[ch * 4 + t] = adj[arow + (size_t)t * NN + gt0 * TM + ch * 16 + l15];

    __syncthreads();   // drains tile-0 DMA (vmcnt); only barrier before loop

    unsigned short* Pw = &Plc[w][0];   // wave-private P scratch [16][PST]

    for (int tile = 0; tile < NTILES; ++tile) {
        const int cur = tile & 1;
        const int nxt = cur ^ 1;

        // ---- issue next-tile DMA; stays in flight all tile ----
        if (tile + 1 < NTILES) {
            const char* src = (const char*)(Hpack + (size_t)(gt0 + tile + 1) * TILE_USH);
            char* dst = (char*)&HH[nxt][0];
            #pragma unroll
            for (int it = 0; it < 9; ++it) {
                int chunk = it * 4 + w;
                if (chunk < TILE_CHUNKS)
                    dma16(src + chunk * 1024 + lofs, dst + chunk * 1024);
            }
        }

        // ---- QK + select + exp, one 16-col ch slice at a time ----
        #pragma unroll
        for (int ch = 0; ch < 4; ++ch) {
            f32x4 S[4];
            #pragma unroll
            for (int k = 0; k < 4; ++k) S[k] = (f32x4){0.f, 0.f, 0.f, 0.f};
            __builtin_amdgcn_s_setprio(1);
            #pragma unroll
            for (int ks = 0; ks < 4; ++ks) {
                bf16x8 B = *(const bf16x8*)&HH[cur][(ch * 16 + l15) * HRS + ks * 32 + 8 * g];
                #pragma unroll
                for (int k = 0; k < 4; ++k)
                    S[k] = __builtin_amdgcn_mfma_f32_16x16x32_bf16(Af[k][ks], B, S[k], 0, 0, 0);
            }
            __builtin_amdgcn_s_setprio(0);
            #pragma unroll
            for (int t = 0; t < 4; ++t) {
                int a = avc[ch * 4 + t];
                float s = S[0][t] + b0;
                s = (a == 2) ? S[1][t] + b1 : s;
                s = (a == 3) ? S[2][t] + b2 : s;
                s = (a == 4) ? S[3][t] + b3 : s;
                float e = fmaxf(s, 0.2f * s);
                float p = __expf(e);           // no-max softmax; scores bounded
                p = (a == 0) ? 0.f : p;
                lrow[t] += p;
                Pw[(4 * g + t) * PST + ch * 16 + l15] = f2bf(p);
            }
        }

        // ---- adj prefetch for next tile (hidden by PV + next QK) ----
        if (tile + 1 < NTILES) {
            #pragma unroll
            for (int ch = 0; ch < 4; ++ch)
                #pragma unroll
                for (int t = 0; t < 4; ++t)
                    avn[ch * 4 + t] = adj[arow + (size_t)t * NN + (size_t)(gt0 + tile + 1) * TM + ch * 16 + l15];
        }

        // ---- PV: no barrier — Pw is wave-private (lgkm-ordered) ----
        __builtin_amdgcn_s_setprio(1);
        #pragma unroll
        for (int kc = 0; kc < 2; ++kc) {
            bf16x8 Pa = *(const bf16x8*)&Pw[l15 * PST + kc * 32 + 8 * g];
            #pragma unroll
            for (int dt = 0; dt < 8; ++dt) {
                bf16x8 Bv = *(const bf16x8*)&HH[cur][HROW_USH + (dt * 16 + l15) * HCS + kc * 32 + 8 * g];
                Oacc[dt] = __builtin_amdgcn_mfma_f32_16x16x32_bf16(Pa, Bv, Oacc[dt], 0, 0, 0);
            }
        }
        __builtin_amdgcn_s_setprio(0);

        #pragma unroll
        for (int i = 0; i < 16; ++i) avc[i] = avn[i];
        __syncthreads();   // vmcnt(0) drain == "HH[nxt] staged"; buffer swap
    }

    // ---- epilogue: rows wave-private; O via fp32 atomics (8 adds/cell) ----
    #pragma unroll
    for (int t = 0; t < 4; ++t) {
        float v = lrow[t];
        v += __shfl_xor(v, 1); v += __shfl_xor(v, 2);
        v += __shfl_xor(v, 4); v += __shfl_xor(v, 8);
        if (l15 == 0) atomicAdd(&lsum[n0 + w * 16 + 4 * g + t], v);
    }
    const int orow0 = n0 + w * 16 + 4 * g;
    #pragma unroll
    for (int dt = 0; dt < 8; ++dt)
        #pragma unroll
        for (int t = 0; t < 4; ++t)
            atomicAdd(&Onum[(size_t)(orow0 + t) * DIM + dt * 16 + l15], Oacc[dt][t]);
}

// ---- combine: trivial divide ----
__global__ __launch_bounds__(256) void combine_kernel(
    const float* __restrict__ Onum, const float* __restrict__ lsum,
    float* __restrict__ out)
{
    int idx = blockIdx.x * 256 + threadIdx.x;
    out[idx] = Onum[idx] / lsum[idx >> 7];
}

extern "C" void kernel_launch(void* const* d_in, const int* in_sizes, int n_in,
                              void* d_out, int out_size, void* d_ws, size_t ws_size,
                              hipStream_t stream) {
    const float* hidden = (const float*)d_in[0];
    const int*   adj    = (const int*)d_in[1];
    const float* W      = (const float*)d_in[2];
    const float* b      = (const float*)d_in[3];
    float* out = (float*)d_out;

    char* ws = (char*)d_ws;
    unsigned short* Hpack = (unsigned short*)ws;                 // 2.29 MB
    float* Onum = (float*)(ws + (4u << 20));                     // 2 MB
    float* lsum = (float*)(ws + (6u << 20));                     // 16 KB
    // zero Onum + lsum in one contiguous memset (graph-capturable)
    hipMemsetAsync(ws + (4u << 20), 0, (2u << 20) + NN * sizeof(float), stream);

    prep_pack_kernel<<<(NN / TM) * 8, 256, 0, stream>>>(hidden, Hpack);
    gat_flash_kernel<<<(NN / TN) * NSPLIT, 256, 0, stream>>>(hidden, Hpack, adj, W, b, Onum, lsum);
    combine_kernel<<<NN * DIM / 256, 256, 0, stream>>>(Onum, lsum, out);
}

// Round 11
// 130.296 us; speedup vs baseline: 1.1680x; 1.0191x over previous
//
#include <hip/hip_runtime.h>

#define NN 4096
#define DIM 128
#define TN 64            // q-rows per block (4 waves x 16 rows)
#define TM 64            // m-tile size
#define NSPLIT 8         // split-m factor (atomic combine)
#define NTILES 8         // tiles per block (64 global tiles / 8)

typedef __attribute__((ext_vector_type(8))) short bf16x8;
typedef __attribute__((ext_vector_type(4))) float f32x4;

#define HRS 136                        // Hrow stride (ushorts, 272 B, 16B-mult)
#define HCS 72                         // Hcol stride (ushorts, 144 B, 16B-mult)
#define HROW_USH (TM * HRS)            // 64*136 = 8704
#define HCOL_USH (128 * HCS)           // 128*72 = 9216
#define TILE_USH (HROW_USH + HCOL_USH) // 17920 ushorts = 35840 B
#define TILE_CHUNKS 35                 // 35840 / 1024
#define PST 72                         // P scratch row stride (ushorts, 16B-mult)

__device__ inline unsigned short f2bf(float x) {
    union { float f; unsigned u; } v; v.f = x;
    unsigned r = v.u + 0x7FFFu + ((v.u >> 16) & 1u);
    return (unsigned short)(r >> 16);
}

// async global->LDS DMA, 16 B/lane, dest = wave-uniform base + lane*16
__device__ inline void dma16(const void* g, void* l) {
    __builtin_amdgcn_global_load_lds(
        (const __attribute__((address_space(1))) void*)g,
        (__attribute__((address_space(3))) void*)l,
        16, 0, 0);
}

// ---- prep (512 blocks = 64 tiles x 8 slices):
//      hidden fp32 -> Hpack[64 tiles][Hrow 64x136 | Hcol 128x72] bf16 ----
__global__ __launch_bounds__(256) void prep_pack_kernel(
    const float* __restrict__ hidden,
    unsigned short* __restrict__ Hpack)
{
    __shared__ unsigned short T[16][HCS];   // transpose slice [d][m]
    const int tid = threadIdx.x;
    const int t0  = blockIdx.x >> 3;   // tile 0..63
    const int s   = blockIdx.x & 7;    // slice 0..7
    const int m0  = t0 * TM;
    unsigned short* rowdst = Hpack + (size_t)t0 * TILE_USH;
    unsigned short* coldst = rowdst + HROW_USH;

    // rows part: rows [8s, 8s+8) x 128 d -> rowdst
    {
        int row = tid >> 5;            // 0..7
        int c4  = (tid & 31) * 4;      // 0..124
        float4 v = *(const float4*)(hidden + (size_t)(m0 + 8 * s + row) * DIM + c4);
        ushort4 o;
        o.x = f2bf(v.x); o.y = f2bf(v.y); o.z = f2bf(v.z); o.w = f2bf(v.w);
        *(ushort4*)(rowdst + (8 * s + row) * HRS + c4) = o;
    }
    // cols part: d in [16s, 16s+16) x 64 m -> T (transposed)
    {
        int m  = tid >> 2;             // 0..63
        int dc = (tid & 3) * 4;        // 0..12
        float4 v = *(const float4*)(hidden + (size_t)(m0 + m) * DIM + 16 * s + dc);
        T[dc + 0][m] = f2bf(v.x);
        T[dc + 1][m] = f2bf(v.y);
        T[dc + 2][m] = f2bf(v.z);
        T[dc + 3][m] = f2bf(v.w);
    }
    __syncthreads();
    if (tid < 128) {
        int d  = tid >> 3;             // 0..15
        int c8 = (tid & 7) * 8;        // m chunk of 8
        uint4 v = *(const uint4*)(&T[d][c8]);
        *(uint4*)(coldst + (16 * s + d) * HCS + c8) = v;
    }
}

// ---- main (round 11): R6 structure with SWAPPED-OPERAND QK (T12-style).
//      Compute S^T = mfma(A = H_j rows from Hrow, B = Af regs): with the
//      verified C/D map (col=lane&15, row=4*(lane>>4)+reg), each lane now
//      owns ONE q-row (q = l15) and j = jt*16 + 4g + t. Consequences:
//        - bf16 pack: 16x f2bf (~80 VALU) -> 8x v_cvt_pk_bf16_f32 (RNE,
//          bit-identical rounding to f2bf);
//        - P staging: 16 scattered ds_write_b16 -> 4 aligned ds_write_b64
//          at Plc row l15; PV's b128 read (row l15) is unchanged;
//        - adj: 16 scalar loads -> 4 int4 loads (64-B segments);
//        - softmax denom: scalar + 2 shuffles.
//      DMA, barriers, double-buffer, PV, epilogue: byte-identical to R6
//      (45.2 us champion). Same-wave cross-lane Plc write->read is the same
//      mechanism R6 already exercises (compiler-inserted lgkmcnt). ----
__global__ __launch_bounds__(256, 2) void gat_flash_kernel(
    const float* __restrict__ hidden,        // fp32 (for Q fragments)
    const unsigned short* __restrict__ Hpack,
    const int*   __restrict__ adj,           // [NN][NN] int32
    const float* __restrict__ W,
    const float* __restrict__ bvec,
    float*       __restrict__ Onum,          // [NN][DIM] fp32, pre-zeroed
    float*       __restrict__ lsum)          // [NN] fp32, pre-zeroed
{
    __shared__ __align__(16) unsigned short HH[2][TILE_USH];   // 71680 B
    __shared__ __align__(16) unsigned short Plc[4][16 * PST];  // 9216 B

    const int tid  = threadIdx.x;
    const int w    = tid >> 6;         // 0..3: wave = 16-row group
    const int lane = tid & 63;
    const int g    = lane >> 4;
    const int l15  = lane & 15;
    const int blk  = blockIdx.x;
    const int nbr  = blk >> 3;         // 0..63 row-group of 64
    const int q8   = blk & 7;          // 0..7 column eighth (== XCD id: L2-local)
    const int n0   = nbr * TN;
    const int gt0  = q8 * NTILES;      // first global tile (of 64)
    const int lofs = lane * 16;

    const float b0 = bvec[0], b1 = bvec[1], b2 = bvec[2], b3 = bvec[3];

    // ---- prologue: DMA tile 0 -> HH[0]; overlaps Af build + adj loads ----
    {
        const char* src = (const char*)(Hpack + (size_t)gt0 * TILE_USH);
        char* dst = (char*)&HH[0][0];
        #pragma unroll
        for (int it = 0; it < 9; ++it) {
            int chunk = it * 4 + w;
            if (chunk < TILE_CHUNKS)
                dma16(src + chunk * 1024 + lofs, dst + chunk * 1024);
        }
    }

    // ---- Af built directly from global (h (.) W_k), no LDS staging.
    //      Layout: lane(g,l15) holds q=l15's d-elems ks*32+8g..+8 — serves as
    //      the MFMA *B* operand in the swapped QK (B[k][col]: col=l15, k=8g..).
    bf16x8 Af[4][4];
    {
        const int qrow = n0 + w * 16 + l15;
        #pragma unroll
        for (int ks = 0; ks < 4; ++ks) {
            const float* hp = hidden + (size_t)qrow * DIM + ks * 32 + 8 * g;
            float4 h0 = *(const float4*)(hp);
            float4 h1 = *(const float4*)(hp + 4);
            #pragma unroll
            for (int k = 0; k < 4; ++k) {
                const float* wp = W + k * DIM + ks * 32 + 8 * g;
                float4 w0 = *(const float4*)(wp);
                float4 w1 = *(const float4*)(wp + 4);
                bf16x8 a;
                a[0] = (short)f2bf(h0.x * w0.x); a[1] = (short)f2bf(h0.y * w0.y);
                a[2] = (short)f2bf(h0.z * w0.z); a[3] = (short)f2bf(h0.w * w0.w);
                a[4] = (short)f2bf(h1.x * w1.x); a[5] = (short)f2bf(h1.y * w1.y);
                a[6] = (short)f2bf(h1.z * w1.z); a[7] = (short)f2bf(h1.w * w1.w);
                Af[k][ks] = a;
            }
        }
    }

    float plsum = 0.f;                 // softmax denom for q = l15 (this lane)
    f32x4 Oacc[8];
    #pragma unroll
    for (int dt = 0; dt < 8; ++dt) Oacc[dt] = (f32x4){0.f, 0.f, 0.f, 0.f};

    // adj codes for tile 0: per lane, row q=l15, 4 consecutive j per jt -> int4
    const int* arow_ptr = adj + (size_t)(n0 + w * 16 + l15) * NN;
    int4 avc[4], avn[4];
    #pragma unroll
    for (int jt = 0; jt < 4; ++jt)
        avc[jt] = *(const int4*)(arow_ptr + gt0 * TM + jt * 16 + 4 * g);

    __syncthreads();   // drains tile-0 DMA (vmcnt); only barrier before loop

    unsigned short* Pw = &Plc[w][0];   // wave-private P scratch [16][PST]

    for (int tile = 0; tile < NTILES; ++tile) {
        const int cur = tile & 1;
        const int nxt = cur ^ 1;

        // ---- issue next-tile DMA; stays in flight all tile ----
        if (tile + 1 < NTILES) {
            const char* src = (const char*)(Hpack + (size_t)(gt0 + tile + 1) * TILE_USH);
            char* dst = (char*)&HH[nxt][0];
            #pragma unroll
            for (int it = 0; it < 9; ++it) {
                int chunk = it * 4 + w;
                if (chunk < TILE_CHUNKS)
                    dma16(src + chunk * 1024 + lofs, dst + chunk * 1024);
            }
        }

        // ---- swapped QK + select + exp, one 16-j slice (jt) at a time.
        //      S[k][t] = S^T[j = jt*16+4g+t][q = l15] ----
        #pragma unroll
        for (int jt = 0; jt < 4; ++jt) {
            f32x4 S[4];
            #pragma unroll
            for (int k = 0; k < 4; ++k) S[k] = (f32x4){0.f, 0.f, 0.f, 0.f};
            #pragma unroll
            for (int ks = 0; ks < 4; ++ks) {
                // A-frag: rows j=jt*16+l15, k-elems d=ks*32+8g.. (same LDS
                // address pattern as R6's B-read — identical traffic)
                bf16x8 Hf = *(const bf16x8*)&HH[cur][(jt * 16 + l15) * HRS + ks * 32 + 8 * g];
                #pragma unroll
                for (int k = 0; k < 4; ++k)
                    S[k] = __builtin_amdgcn_mfma_f32_16x16x32_bf16(Hf, Af[k][ks], S[k], 0, 0, 0);
            }
            const int4 av = avc[jt];
            float p[4];
            #pragma unroll
            for (int t = 0; t < 4; ++t) {
                const int a = (t == 0) ? av.x : (t == 1) ? av.y : (t == 2) ? av.z : av.w;
                float s = S[0][t] + b0;
                s = (a == 2) ? S[1][t] + b1 : s;
                s = (a == 3) ? S[2][t] + b2 : s;
                s = (a == 4) ? S[3][t] + b3 : s;
                float e = fmaxf(s, 0.2f * s);
                float pp = __expf(e);          // no-max softmax; scores bounded
                pp = (a == 0) ? 0.f : pp;
                plsum += pp;
                p[t] = pp;
            }
            // pack 4 probs (j = jt*16+4g+0..3) as bf16 RNE via cvt_pk, store 8 B
            unsigned r01, r23;
            asm("v_cvt_pk_bf16_f32 %0, %1, %2" : "=v"(r01) : "v"(p[0]), "v"(p[1]));
            asm("v_cvt_pk_bf16_f32 %0, %1, %2" : "=v"(r23) : "v"(p[2]), "v"(p[3]));
            uint2 r2; r2.x = r01; r2.y = r23;
            *(uint2*)(Pw + l15 * PST + jt * 16 + 4 * g) = r2;   // 8B-aligned
        }

        // ---- adj prefetch for next tile (hidden by PV + next QK) ----
        if (tile + 1 < NTILES) {
            #pragma unroll
            for (int jt = 0; jt < 4; ++jt)
                avn[jt] = *(const int4*)(arow_ptr + (gt0 + tile + 1) * TM + jt * 16 + 4 * g);
        }

        // ---- PV: unchanged from R6 — Pa row l15 (now written directly by
        //      the swapped layout); no barrier (wave-private, lgkm-ordered) ----
        #pragma unroll
        for (int kc = 0; kc < 2; ++kc) {
            bf16x8 Pa = *(const bf16x8*)&Pw[l15 * PST + kc * 32 + 8 * g];
            #pragma unroll
            for (int dt = 0; dt < 8; ++dt) {
                bf16x8 Bv = *(const bf16x8*)&HH[cur][HROW_USH + (dt * 16 + l15) * HCS + kc * 32 + 8 * g];
                Oacc[dt] = __builtin_amdgcn_mfma_f32_16x16x32_bf16(Pa, Bv, Oacc[dt], 0, 0, 0);
            }
        }

        #pragma unroll
        for (int i = 0; i < 4; ++i) avc[i] = avn[i];
        __syncthreads();   // vmcnt(0) drain == "HH[nxt] staged"; buffer swap
    }

    // ---- epilogue: q = l15 per lane; sum over the 4 g-groups via shuffles ----
    {
        float v = plsum;
        v += __shfl_xor(v, 16);
        v += __shfl_xor(v, 32);
        if (lane < 16) atomicAdd(&lsum[n0 + w * 16 + l15], v);
    }
    const int orow0 = n0 + w * 16 + 4 * g;
    #pragma unroll
    for (int dt = 0; dt < 8; ++dt)
        #pragma unroll
        for (int t = 0; t < 4; ++t)
            atomicAdd(&Onum[(size_t)(orow0 + t) * DIM + dt * 16 + l15], Oacc[dt][t]);
}

// ---- combine: trivial divide ----
__global__ __launch_bounds__(256) void combine_kernel(
    const float* __restrict__ Onum, const float* __restrict__ lsum,
    float* __restrict__ out)
{
    int idx = blockIdx.x * 256 + threadIdx.x;
    out[idx] = Onum[idx] / lsum[idx >> 7];
}

extern "C" void kernel_launch(void* const* d_in, const int* in_sizes, int n_in,
                              void* d_out, int out_size, void* d_ws, size_t ws_size,
                              hipStream_t stream) {
    const float* hidden = (const float*)d_in[0];
    const int*   adj    = (const int*)d_in[1];
    const float* W      = (const float*)d_in[2];
    const float* b      = (const float*)d_in[3];
    float* out = (float*)d_out;

    char* ws = (char*)d_ws;
    unsigned short* Hpack = (unsigned short*)ws;                 // 2.29 MB
    float* Onum = (float*)(ws + (4u << 20));                     // 2 MB
    float* lsum = (float*)(ws + (6u << 20));                     // 16 KB
    // zero Onum + lsum in one contiguous memset (graph-capturable)
    hipMemsetAsync(ws + (4u << 20), 0, (2u << 20) + NN * sizeof(float), stream);

    prep_pack_kernel<<<(NN / TM) * 8, 256, 0, stream>>>(hidden, Hpack);
    gat_flash_kernel<<<(NN / TN) * NSPLIT, 256, 0, stream>>>(hidden, Hpack, adj, W, b, Onum, lsum);
    combine_kernel<<<NN * DIM / 256, 256, 0, stream>>>(Onum, lsum, out);
}

// Round 12
// 128.633 us; speedup vs baseline: 1.1831x; 1.0129x over previous
//
#include <hip/hip_runtime.h>

#define NN 4096
#define DIM 128
#define TN 64            // q-rows per block (4 waves x 16 rows)
#define TM 64            // m-tile size
#define NSPLIT 8         // split-m factor (atomic combine)
#define NTILES 8         // tiles per block (64 global tiles / 8)

typedef __attribute__((ext_vector_type(8))) short bf16x8;
typedef __attribute__((ext_vector_type(4))) float f32x4;
typedef __attribute__((ext_vector_type(4))) unsigned u32x4;

#define HRS 136                        // Hrow stride (ushorts, 272 B, 16B-mult)
#define HCS 72                         // Hcol stride (ushorts, 144 B, 16B-mult)
#define HROW_USH (TM * HRS)            // 64*136 = 8704
#define HCOL_USH (128 * HCS)           // 128*72 = 9216
#define TILE_USH (HROW_USH + HCOL_USH) // 17920 ushorts = 35840 B
#define TILE_CHUNKS 35                 // 35840 / 1024

__device__ inline unsigned short f2bf(float x) {
    union { float f; unsigned u; } v; v.f = x;
    unsigned r = v.u + 0x7FFFu + ((v.u >> 16) & 1u);
    return (unsigned short)(r >> 16);
}

// async global->LDS DMA, 16 B/lane, dest = wave-uniform base + lane*16
__device__ inline void dma16(const void* g, void* l) {
    __builtin_amdgcn_global_load_lds(
        (const __attribute__((address_space(1))) void*)g,
        (__attribute__((address_space(3))) void*)l,
        16, 0, 0);
}

// ---- prep (512 blocks = 64 tiles x 8 slices):
//      hidden fp32 -> Hpack[64 tiles][Hrow 64x136 PERMUTED | Hcol 128x72] bf16
//      Hrow row order is bit-permuted (phys[b5..b0] = [j2,j5,j4,j3,j1,j0]) so
//      the main kernel's swapped-QK output lands with j = 32kc+8g+e per lane —
//      exactly PV's A-fragment layout (P never touches LDS). ----
__global__ __launch_bounds__(256) void prep_pack_kernel(
    const float* __restrict__ hidden,
    unsigned short* __restrict__ Hpack)
{
    __shared__ unsigned short T[16][HCS];   // transpose slice [d][m]
    const int tid = threadIdx.x;
    const int t0  = blockIdx.x >> 3;   // tile 0..63
    const int s   = blockIdx.x & 7;    // slice 0..7
    const int m0  = t0 * TM;
    unsigned short* rowdst = Hpack + (size_t)t0 * TILE_USH;
    unsigned short* coldst = rowdst + HROW_USH;

    // rows part: logical rows [8s, 8s+8) x 128 d -> permuted physical rows
    {
        int row = tid >> 5;            // 0..7
        int c4  = (tid & 31) * 4;      // 0..124
        int j   = 8 * s + row;         // logical row in tile (0..63)
        int pj  = ((j >> 2) & 1) * 32 + ((j >> 5) & 1) * 16
                + ((j >> 3) & 3) * 4  + (j & 3);          // bijective bit-perm
        float4 v = *(const float4*)(hidden + (size_t)(m0 + j) * DIM + c4);
        ushort4 o;
        o.x = f2bf(v.x); o.y = f2bf(v.y); o.z = f2bf(v.z); o.w = f2bf(v.w);
        *(ushort4*)(rowdst + pj * HRS + c4) = o;
    }
    // cols part: d in [16s, 16s+16) x 64 m -> T (transposed); m-order LINEAR
    {
        int m  = tid >> 2;             // 0..63
        int dc = (tid & 3) * 4;        // 0..12
        float4 v = *(const float4*)(hidden + (size_t)(m0 + m) * DIM + 16 * s + dc);
        T[dc + 0][m] = f2bf(v.x);
        T[dc + 1][m] = f2bf(v.y);
        T[dc + 2][m] = f2bf(v.z);
        T[dc + 3][m] = f2bf(v.w);
    }
    __syncthreads();
    if (tid < 128) {
        int d  = tid >> 3;             // 0..15
        int c8 = (tid & 7) * 8;        // m chunk of 8
        uint4 v = *(const uint4*)(&T[d][c8]);
        *(uint4*)(coldst + (16 * s + d) * HCS + c8) = v;
    }
}

// ---- main (round 12): R11 + REGISTER-RESIDENT P via permuted Hrow order.
//      Swapped QK slice s reads physical rows 16s+l15 (identical addresses/
//      banks to R11) which hold logical j = 32(s&1)+8g+4(s>>1)+t at output
//      lane (g,l15). cvt_pk pairs drop straight into Pa[kc] u32 words:
//      after 4 slices each lane holds P[q=l15][32kc+8g+0..7] in registers —
//      PV's A-fragment, no ds_write/ds_read/lgkm round-trip, Plc deleted.
//      Everything else (DMA double-buffer, one barrier/tile, wave-private
//      rows, atomic combine, numerics incl. RNE pack + kc0->kc1 order)
//      identical to R11 (45.4 us champion-equal). ----
__global__ __launch_bounds__(256, 2) void gat_flash_kernel(
    const float* __restrict__ hidden,        // fp32 (for Q fragments)
    const unsigned short* __restrict__ Hpack,
    const int*   __restrict__ adj,           // [NN][NN] int32
    const float* __restrict__ W,
    const float* __restrict__ bvec,
    float*       __restrict__ Onum,          // [NN][DIM] fp32, pre-zeroed
    float*       __restrict__ lsum)          // [NN] fp32, pre-zeroed
{
    __shared__ __align__(16) unsigned short HH[2][TILE_USH];   // 71680 B (only LDS)

    const int tid  = threadIdx.x;
    const int w    = tid >> 6;         // 0..3: wave = 16-row group
    const int lane = tid & 63;
    const int g    = lane >> 4;
    const int l15  = lane & 15;
    const int blk  = blockIdx.x;
    const int nbr  = blk >> 3;         // 0..63 row-group of 64
    const int q8   = blk & 7;          // 0..7 column eighth (== XCD id: L2-local)
    const int n0   = nbr * TN;
    const int gt0  = q8 * NTILES;      // first global tile (of 64)
    const int lofs = lane * 16;

    const float b0 = bvec[0], b1 = bvec[1], b2 = bvec[2], b3 = bvec[3];

    // ---- prologue: DMA tile 0 -> HH[0]; overlaps Af build + adj loads ----
    {
        const char* src = (const char*)(Hpack + (size_t)gt0 * TILE_USH);
        char* dst = (char*)&HH[0][0];
        #pragma unroll
        for (int it = 0; it < 9; ++it) {
            int chunk = it * 4 + w;
            if (chunk < TILE_CHUNKS)
                dma16(src + chunk * 1024 + lofs, dst + chunk * 1024);
        }
    }

    // ---- Af built directly from global (h (.) W_k): B-operand of swapped QK.
    bf16x8 Af[4][4];
    {
        const int qrow = n0 + w * 16 + l15;
        #pragma unroll
        for (int ks = 0; ks < 4; ++ks) {
            const float* hp = hidden + (size_t)qrow * DIM + ks * 32 + 8 * g;
            float4 h0 = *(const float4*)(hp);
            float4 h1 = *(const float4*)(hp + 4);
            #pragma unroll
            for (int k = 0; k < 4; ++k) {
                const float* wp = W + k * DIM + ks * 32 + 8 * g;
                float4 w0 = *(const float4*)(wp);
                float4 w1 = *(const float4*)(wp + 4);
                bf16x8 a;
                a[0] = (short)f2bf(h0.x * w0.x); a[1] = (short)f2bf(h0.y * w0.y);
                a[2] = (short)f2bf(h0.z * w0.z); a[3] = (short)f2bf(h0.w * w0.w);
                a[4] = (short)f2bf(h1.x * w1.x); a[5] = (short)f2bf(h1.y * w1.y);
                a[6] = (short)f2bf(h1.z * w1.z); a[7] = (short)f2bf(h1.w * w1.w);
                Af[k][ks] = a;
            }
        }
    }

    float plsum = 0.f;                 // softmax denom for q = l15 (this lane)
    f32x4 Oacc[8];
    #pragma unroll
    for (int dt = 0; dt < 8; ++dt) Oacc[dt] = (f32x4){0.f, 0.f, 0.f, 0.f};

    // adj codes, tile 0: slice s covers j = 32(s&1) + 8g + 4(s>>1) + 0..3 -> int4
    const int* arow_ptr = adj + (size_t)(n0 + w * 16 + l15) * NN;
    const int joff0 = 8 * g;                          // s=0: kc0,h0
    const int joff1 = 32 + 8 * g;                     // s=1: kc1,h0
    const int joff2 = 8 * g + 4;                      // s=2: kc0,h1
    const int joff3 = 32 + 8 * g + 4;                 // s=3: kc1,h1
    int4 avc[4], avn[4];
    avc[0] = *(const int4*)(arow_ptr + gt0 * TM + joff0);
    avc[1] = *(const int4*)(arow_ptr + gt0 * TM + joff1);
    avc[2] = *(const int4*)(arow_ptr + gt0 * TM + joff2);
    avc[3] = *(const int4*)(arow_ptr + gt0 * TM + joff3);

    __syncthreads();   // drains tile-0 DMA (vmcnt); only barrier before loop

    for (int tile = 0; tile < NTILES; ++tile) {
        const int cur = tile & 1;
        const int nxt = cur ^ 1;

        // ---- issue next-tile DMA; stays in flight all tile ----
        if (tile + 1 < NTILES) {
            const char* src = (const char*)(Hpack + (size_t)(gt0 + tile + 1) * TILE_USH);
            char* dst = (char*)&HH[nxt][0];
            #pragma unroll
            for (int it = 0; it < 9; ++it) {
                int chunk = it * 4 + w;
                if (chunk < TILE_CHUNKS)
                    dma16(src + chunk * 1024 + lofs, dst + chunk * 1024);
            }
        }

        // ---- swapped QK + select + exp per slice; pack into Pa regs ----
        u32x4 paw0, paw1;   // PV A-frag words: kc=0 / kc=1

#define QK_SLICE(S, W0, W1)                                                        \
        {                                                                          \
            f32x4 Sv[4];                                                           \
            _Pragma("unroll")                                                      \
            for (int k = 0; k < 4; ++k) Sv[k] = (f32x4){0.f, 0.f, 0.f, 0.f};       \
            _Pragma("unroll")                                                      \
            for (int ks = 0; ks < 4; ++ks) {                                       \
                bf16x8 Hf = *(const bf16x8*)&HH[cur][((S) * 16 + l15) * HRS + ks * 32 + 8 * g]; \
                _Pragma("unroll")                                                  \
                for (int k = 0; k < 4; ++k)                                        \
                    Sv[k] = __builtin_amdgcn_mfma_f32_16x16x32_bf16(Hf, Af[k][ks], Sv[k], 0, 0, 0); \
            }                                                                      \
            const int4 av = avc[S];                                                \
            float p[4];                                                            \
            _Pragma("unroll")                                                      \
            for (int t = 0; t < 4; ++t) {                                          \
                const int a = (t == 0) ? av.x : (t == 1) ? av.y : (t == 2) ? av.z : av.w; \
                float sc = Sv[0][t] + b0;                                          \
                sc = (a == 2) ? Sv[1][t] + b1 : sc;                                \
                sc = (a == 3) ? Sv[2][t] + b2 : sc;                                \
                sc = (a == 4) ? Sv[3][t] + b3 : sc;                                \
                float e = fmaxf(sc, 0.2f * sc);                                    \
                float pp = __expf(e);          /* no-max softmax; bounded */       \
                pp = (a == 0) ? 0.f : pp;                                          \
                plsum += pp;                                                       \
                p[t] = pp;                                                         \
            }                                                                      \
            unsigned r01, r23;                                                     \
            asm("v_cvt_pk_bf16_f32 %0, %1, %2" : "=v"(r01) : "v"(p[0]), "v"(p[1])); \
            asm("v_cvt_pk_bf16_f32 %0, %1, %2" : "=v"(r23) : "v"(p[2]), "v"(p[3])); \
            W0 = r01; W1 = r23;                                                    \
        }

        QK_SLICE(0, paw0.x, paw0.y)    // kc=0, e=0..3
        QK_SLICE(1, paw1.x, paw1.y)    // kc=1, e=0..3
        QK_SLICE(2, paw0.z, paw0.w)    // kc=0, e=4..7
        QK_SLICE(3, paw1.z, paw1.w)    // kc=1, e=4..7
#undef QK_SLICE

        // ---- adj prefetch for next tile (hidden by PV + next QK) ----
        if (tile + 1 < NTILES) {
            const int* ap = arow_ptr + (gt0 + tile + 1) * TM;
            avn[0] = *(const int4*)(ap + joff0);
            avn[1] = *(const int4*)(ap + joff1);
            avn[2] = *(const int4*)(ap + joff2);
            avn[3] = *(const int4*)(ap + joff3);
        }

        // ---- PV: Pa straight from registers (no LDS round-trip, no lgkm) ----
        {
            bf16x8 Pa0 = __builtin_bit_cast(bf16x8, paw0);
            bf16x8 Pa1 = __builtin_bit_cast(bf16x8, paw1);
            #pragma unroll
            for (int dt = 0; dt < 8; ++dt) {
                bf16x8 Bv0 = *(const bf16x8*)&HH[cur][HROW_USH + (dt * 16 + l15) * HCS + 8 * g];
                Oacc[dt] = __builtin_amdgcn_mfma_f32_16x16x32_bf16(Pa0, Bv0, Oacc[dt], 0, 0, 0);
            }
            #pragma unroll
            for (int dt = 0; dt < 8; ++dt) {
                bf16x8 Bv1 = *(const bf16x8*)&HH[cur][HROW_USH + (dt * 16 + l15) * HCS + 32 + 8 * g];
                Oacc[dt] = __builtin_amdgcn_mfma_f32_16x16x32_bf16(Pa1, Bv1, Oacc[dt], 0, 0, 0);
            }
        }

        #pragma unroll
        for (int i = 0; i < 4; ++i) avc[i] = avn[i];
        __syncthreads();   // vmcnt(0) drain == "HH[nxt] staged"; buffer swap
    }

    // ---- epilogue: q = l15 per lane; sum over the 4 g-groups via shuffles ----
    {
        float v = plsum;
        v += __shfl_xor(v, 16);
        v += __shfl_xor(v, 32);
        if (lane < 16) atomicAdd(&lsum[n0 + w * 16 + l15], v);
    }
    const int orow0 = n0 + w * 16 + 4 * g;
    #pragma unroll
    for (int dt = 0; dt < 8; ++dt)
        #pragma unroll
        for (int t = 0; t < 4; ++t)
            atomicAdd(&Onum[(size_t)(orow0 + t) * DIM + dt * 16 + l15], Oacc[dt][t]);
}

// ---- combine: trivial divide ----
__global__ __launch_bounds__(256) void combine_kernel(
    const float* __restrict__ Onum, const float* __restrict__ lsum,
    float* __restrict__ out)
{
    int idx = blockIdx.x * 256 + threadIdx.x;
    out[idx] = Onum[idx] / lsum[idx >> 7];
}

extern "C" void kernel_launch(void* const* d_in, const int* in_sizes, int n_in,
                              void* d_out, int out_size, void* d_ws, size_t ws_size,
                              hipStream_t stream) {
    const float* hidden = (const float*)d_in[0];
    const int*   adj    = (const int*)d_in[1];
    const float* W      = (const float*)d_in[2];
    const float* b      = (const float*)d_in[3];
    float* out = (float*)d_out;

    char* ws = (char*)d_ws;
    unsigned short* Hpack = (unsigned short*)ws;                 // 2.29 MB
    float* Onum = (float*)(ws + (4u << 20));                     // 2 MB
    float* lsum = (float*)(ws + (6u << 20));                     // 16 KB
    // zero Onum + lsum in one contiguous memset (graph-capturable)
    hipMemsetAsync(ws + (4u << 20), 0, (2u << 20) + NN * sizeof(float), stream);

    prep_pack_kernel<<<(NN / TM) * 8, 256, 0, stream>>>(hidden, Hpack);
    gat_flash_kernel<<<(NN / TN) * NSPLIT, 256, 0, stream>>>(hidden, Hpack, adj, W, b, Onum, lsum);
    combine_kernel<<<NN * DIM / 256, 256, 0, stream>>>(Onum, lsum, out);
}